// Round 12
// baseline (991.157 us; speedup 1.0000x reference)
//
#include <hip/hip_runtime.h>
#include <hip/hip_bf16.h>

// ---------------------------------------------------------------------------
// GCN via agg-commute: agg(XW) == agg(X)W. z = dinv (.) h stored bf16 PLANAR:
// 8 planes x 16 channels (N x 32B per plane, 3.2MB).
// R21: XCD-bound channel-plane gather. Each gather block reads its physical
//   XCD id (s_getreg HW_REG_XCC_ID, m09-verified) and gathers ONLY that
//   plane -> per-XCD L2 working set 3.2MB plane + 0.4MB packed row meta
//   (< 4MB L2) -> ~99% hit rate vs 55% (fetch 187MB -> ~35MB predicted).
//   Work = (slice, 256-node tickets) from global atomic counters with an
//   8-slice stealing sweep: exactly-once coverage under ANY block->XCD
//   mapping (correctness never depends on dispatch heuristics).
//   gather writes A planar with NT stores (streaming consumer; keeps Z plane
//   resident). gemm_layer reads A fragments DIRECTLY from global (planar
//   layout makes each wave's MFMA A-load one contiguous 2KB region - no LDS
//   staging; layer 1 has zero barriers). Layer-2's dead 25.6MB z2 store
//   (carried since R14) dropped. P=z2@W3 path + agg_pool + build unchanged.
// ---------------------------------------------------------------------------

#define THREADS 256
#define BSHIFT 9
#define BSIZE 512
#define SREG 12288  // static slots per bucket region
#define NSL 8       // channel planes == XCDs

typedef __attribute__((ext_vector_type(8))) short short8;
typedef __attribute__((ext_vector_type(16))) float floatx16;
typedef __attribute__((ext_vector_type(2))) unsigned int uintx2;

__device__ __forceinline__ unsigned f2bf(float f) {  // fp32 -> bf16 bits, RNE
    unsigned u = __float_as_uint(f);
    return (u + 0x7fffu + ((u >> 16) & 1u)) >> 16;
}

__device__ __forceinline__ void bf8_acc(uint4 v, float* ac) {
    ac[0] += __uint_as_float(v.x << 16);
    ac[1] += __uint_as_float(v.x & 0xffff0000u);
    ac[2] += __uint_as_float(v.y << 16);
    ac[3] += __uint_as_float(v.y & 0xffff0000u);
    ac[4] += __uint_as_float(v.z << 16);
    ac[5] += __uint_as_float(v.z & 0xffff0000u);
    ac[6] += __uint_as_float(v.w << 16);
    ac[7] += __uint_as_float(v.w & 0xffff0000u);
}

__device__ __forceinline__ void bf4_acc(uint2 v, float* ac) {
    ac[0] += __uint_as_float(v.x << 16);
    ac[1] += __uint_as_float(v.x & 0xffff0000u);
    ac[2] += __uint_as_float(v.y << 16);
    ac[3] += __uint_as_float(v.y & 0xffff0000u);
}

// ---- prep: W^T bf16 pack helper --------------------------------------------
__device__ __forceinline__ void wt_pack(const float* W, uint4* Wtp, int C, int li) {
    int c = li >> 4, ch = li & 15;
    unsigned r[8];
#pragma unroll
    for (int j = 0; j < 8; ++j) r[j] = f2bf(W[(size_t)(ch * 8 + j) * C + c]);
    uint4 o;
    o.x = r[0] | (r[1] << 16);
    o.y = r[2] | (r[3] << 16);
    o.z = r[4] | (r[5] << 16);
    o.w = r[6] | (r[7] << 16);
    Wtp[li] = o;
}

// ---- bucketed scatter to static regions ------------------------------------
__global__ __launch_bounds__(THREADS) void bucket_scatter(const int* __restrict__ src,
                                                          const int* __restrict__ dst,
                                                          int* __restrict__ bcursor,
                                                          int* __restrict__ pairs,
                                                          int E, int nscat,
                                                          const float* __restrict__ W1,
                                                          const float* __restrict__ W2,
                                                          const float* __restrict__ W3,
                                                          uint4* __restrict__ Wt1,
                                                          uint4* __restrict__ Wt2,
                                                          uint4* __restrict__ Wt3) {
    if (blockIdx.x >= nscat) {
        int k = (blockIdx.x - nscat) * THREADS + threadIdx.x;
        if (k < 2048) wt_pack(W1, Wt1, 128, k);
        else if (k < 4096) wt_pack(W2, Wt2, 128, k - 2048);
        else if (k < 5120) wt_pack(W3, Wt3, 64, k - 4096);
        return;
    }
    __shared__ int cnt[BSIZE];
    __shared__ int base[BSIZE];
    for (int i = threadIdx.x; i < BSIZE; i += THREADS) cnt[i] = 0;
    __syncthreads();
    int e0 = blockIdx.x * 4096;
    int myb[16], myrank[16], mypk[16];
#pragma unroll
    for (int j = 0; j < 16; ++j) {
        int e = e0 + j * THREADS + threadIdx.x;
        myb[j] = -1;
        if (e < E) {
            int d = dst[e];
            mypk[j] = (src[e] << BSHIFT) | (d & (BSIZE - 1));
            myb[j] = d >> BSHIFT;
            myrank[j] = atomicAdd(&cnt[myb[j]], 1);
        }
    }
    __syncthreads();
    for (int i = threadIdx.x; i < BSIZE; i += THREADS) {
        int c = cnt[i];
        base[i] = c ? atomicAdd(&bcursor[i], c) : 0;
    }
    __syncthreads();
#pragma unroll
    for (int j = 0; j < 16; ++j)
        if (myb[j] >= 0) {
            int pos = base[myb[j]] + myrank[j];
            if (pos < SREG)
                pairs[(size_t)myb[j] * SREG + pos] = mypk[j];
        }
}

// one block per bucket, 1024 threads: histogram/scan -> row_start/row_end,
// pmeta=(rs<<9|deg), dinv, esrc; fused prep_x writes z1 PLANAR.
__global__ __launch_bounds__(1024) void bucket_fill(const int* __restrict__ pairs,
                                                    const int* __restrict__ bcount,
                                                    int* __restrict__ row_start,
                                                    int* __restrict__ row_end,
                                                    int* __restrict__ pmeta,
                                                    float* __restrict__ dinv,
                                                    int* __restrict__ esrc,
                                                    const float* __restrict__ x,
                                                    uint4* __restrict__ Zp, int N) {
    __shared__ int cnt[BSIZE];
    __shared__ int scn[BSIZE];
    __shared__ float sdv[BSIZE];
    int b = blockIdx.x, t = threadIdx.x;
    size_t rbase = (size_t)b * SREG;
    int total = bcount[b];
    if (total > SREG) total = SREG;
    if (t < BSIZE) cnt[t] = 0;
    __syncthreads();
    for (int i = t; i < total; i += 1024) atomicAdd(&cnt[pairs[rbase + i] & (BSIZE - 1)], 1);
    __syncthreads();
    int v = 0;
    if (t < BSIZE) {
        v = cnt[t];
        scn[t] = v;
    }
    __syncthreads();
    for (int off = 1; off < 512; off <<= 1) {
        int tv = (t >= off && t < BSIZE) ? scn[t - off] : 0;
        __syncthreads();
        if (t < BSIZE) scn[t] += tv;
        __syncthreads();
    }
    if (t < BSIZE) {
        int excl = scn[t] - v;
        int g = (b << BSHIFT) + t;
        float dv = rsqrtf(1.0f + (float)v);  // deg = 1 + in-degree (self-loop)
        if (g < N) {
            int rs = (int)rbase + excl;
            row_start[g] = rs;
            row_end[g] = rs + v;
            int dcl = (v < 511) ? v : 511;  // binomially impossible; guard pack
            pmeta[g] = (rs << 9) | dcl;
            dinv[g] = dv;
        }
        sdv[t] = dv;
        scn[t] = excl;  // reuse as cursor
    }
    __syncthreads();
    for (int i = t; i < total; i += 1024) {
        int p = pairs[rbase + i];
        int r = atomicAdd(&scn[p & (BSIZE - 1)], 1);
        esrc[rbase + r] = ((unsigned)p) >> BSHIFT;
    }
    // ---- fused prep_x: planar z1, dinv from LDS ----
    int g0 = b << BSHIFT;
    for (int idx = t; idx < BSIZE * 16; idx += 1024) {
        int rl = idx >> 4;
        int g = g0 + rl;
        if (g >= N) break;  // rl monotonic per thread
        int c = idx & 15;
        float dv = sdv[rl];
        const float* p = x + (size_t)g * 128 + c * 8;
        float4 a = *(const float4*)p;
        float4 bb = *(const float4*)(p + 4);
        uint4 o;
        o.x = f2bf(a.x * dv) | (f2bf(a.y * dv) << 16);
        o.y = f2bf(a.z * dv) | (f2bf(a.w * dv) << 16);
        o.z = f2bf(bb.x * dv) | (f2bf(bb.y * dv) << 16);
        o.w = f2bf(bb.z * dv) | (f2bf(bb.w * dv) << 16);
        Zp[((size_t)(c >> 1) * N + g) * 2 + (c & 1)] = o;  // plane c>>1, half c&1
    }
}

// ---- XCD-bound planar gather: A[s][node] = dinv*(sum z[s][src] + z[s][i]) --
// Tickets: (slice, 256-node block). Stealing sweep guarantees exactly-once
// coverage under any block->XCD mapping; XCC_ID only steers locality.
__global__ __launch_bounds__(THREADS) void gather_slice(const uint2* __restrict__ Zp,
                                                        const int* __restrict__ pmeta,
                                                        const int* __restrict__ esrc,
                                                        const uint2* __restrict__ zrow2,
                                                        uint2* __restrict__ Ap,
                                                        int* __restrict__ wctr,
                                                        int n, int ntick) {
    __shared__ int snb;
    int tid = threadIdx.x;
    int lane = tid & 3, grp = tid >> 2;  // 4 lanes x 64 nodes
    // physical XCD id: hwreg 20 (HW_REG_XCC_ID), offset 0, width 32 -> 0xF814
    int myx = (int)(__builtin_amdgcn_s_getreg(0xF814) & (NSL - 1));
    const uint2* zl = zrow2 + lane;
    for (int sv = 0; sv < NSL; ++sv) {
        int sl = (myx + sv) & (NSL - 1);
        const uint2* Zs = Zp + (size_t)sl * n * 4;
        uint2* As = Ap + (size_t)sl * n * 4;
        for (;;) {
            __syncthreads();
            if (tid == 0) snb = atomicAdd(&wctr[sl], 1);
            __syncthreads();
            int nb = snb;
            if (nb >= ntick) break;
            int base = nb * 256;
            for (int r4 = 0; r4 < 4; ++r4) {
                int node = base + r4 * 64 + grp;
                int nd = (node < n) ? node : (n - 1);
                unsigned mt = (unsigned)pmeta[nd];
                int rs = (int)(mt >> 9);
                int deg = (int)(mt & 511u);
                int e = rs + deg;
                float dv = rsqrtf(1.0f + (float)deg);
                float ac[4] = {0.f, 0.f, 0.f, 0.f};
                bf4_acc(Zs[(size_t)nd * 4 + lane], ac);  // self term
                int i = rs;
                int nmain = deg >> 3;
                if (nmain > 0) {
                    int s0 = esrc[i], s1 = esrc[i + 1], s2 = esrc[i + 2], s3 = esrc[i + 3];
                    int s4 = esrc[i + 4], s5 = esrc[i + 5], s6 = esrc[i + 6], s7 = esrc[i + 7];
                    for (int m = 0; m < nmain; ++m) {
                        uint2 v0 = Zs[(size_t)s0 * 4 + lane];
                        uint2 v1 = Zs[(size_t)s1 * 4 + lane];
                        uint2 v2 = Zs[(size_t)s2 * 4 + lane];
                        uint2 v3 = Zs[(size_t)s3 * 4 + lane];
                        uint2 v4 = Zs[(size_t)s4 * 4 + lane];
                        uint2 v5 = Zs[(size_t)s5 * 4 + lane];
                        uint2 v6 = Zs[(size_t)s6 * 4 + lane];
                        uint2 v7 = Zs[(size_t)s7 * 4 + lane];
                        int ni = i + 8;
                        int t0 = esrc[ni], t1 = esrc[ni + 1], t2 = esrc[ni + 2], t3 = esrc[ni + 3];
                        int t4 = esrc[ni + 4], t5 = esrc[ni + 5], t6 = esrc[ni + 6], t7 = esrc[ni + 7];
                        bf4_acc(v0, ac); bf4_acc(v1, ac); bf4_acc(v2, ac); bf4_acc(v3, ac);
                        bf4_acc(v4, ac); bf4_acc(v5, ac); bf4_acc(v6, ac); bf4_acc(v7, ac);
                        s0 = t0; s1 = t1; s2 = t2; s3 = t3;
                        s4 = t4; s5 = t5; s6 = t6; s7 = t7;
                        i = ni;
                    }
                }
                if (i < e) {  // masked branchless 8-wide tail
                    const uint2* p0 = (i + 0 < e) ? (Zs + ((size_t)esrc[i + 0] * 4 + lane)) : zl;
                    const uint2* p1 = (i + 1 < e) ? (Zs + ((size_t)esrc[i + 1] * 4 + lane)) : zl;
                    const uint2* p2 = (i + 2 < e) ? (Zs + ((size_t)esrc[i + 2] * 4 + lane)) : zl;
                    const uint2* p3 = (i + 3 < e) ? (Zs + ((size_t)esrc[i + 3] * 4 + lane)) : zl;
                    const uint2* p4 = (i + 4 < e) ? (Zs + ((size_t)esrc[i + 4] * 4 + lane)) : zl;
                    const uint2* p5 = (i + 5 < e) ? (Zs + ((size_t)esrc[i + 5] * 4 + lane)) : zl;
                    const uint2* p6 = (i + 6 < e) ? (Zs + ((size_t)esrc[i + 6] * 4 + lane)) : zl;
                    const uint2* p7 = (i + 7 < e) ? (Zs + ((size_t)esrc[i + 7] * 4 + lane)) : zl;
                    uint2 v0 = *p0; uint2 v1 = *p1; uint2 v2 = *p2; uint2 v3 = *p3;
                    uint2 v4 = *p4; uint2 v5 = *p5; uint2 v6 = *p6; uint2 v7 = *p7;
                    bf4_acc(v0, ac); bf4_acc(v1, ac); bf4_acc(v2, ac); bf4_acc(v3, ac);
                    bf4_acc(v4, ac); bf4_acc(v5, ac); bf4_acc(v6, ac); bf4_acc(v7, ac);
                }
                if (node < n) {
                    uintx2 pk;
                    pk[0] = f2bf(ac[0] * dv) | (f2bf(ac[1] * dv) << 16);
                    pk[1] = f2bf(ac[2] * dv) | (f2bf(ac[3] * dv) << 16);
                    // NT: streaming consumer; don't evict the resident Z plane
                    __builtin_nontemporal_store(pk, (uintx2*)&As[(size_t)node * 4 + lane]);
                }
            }
        }
    }
}

// ---- gemm layer: A (planar global) @ W -> +bias, relu, x dinv ---------------
// outZ: planar z_next (layer 1) or null. outP: Ps row-major (layer 2) or null.
__global__ __launch_bounds__(THREADS) void gemm_layer(const uint4* __restrict__ Ap4,
                                                      const uint4* __restrict__ Wt,
                                                      const float* __restrict__ dinv,
                                                      const float* __restrict__ bias,
                                                      uint2* __restrict__ outZ,
                                                      const uint4* __restrict__ WtP,
                                                      uint4* __restrict__ outP, int n) {
    __shared__ __align__(16) uint4 ldsX[64 * 16];  // used only on the P path
    int row0 = blockIdx.x * 64;
    int maxr = n - row0;
    if (maxr > 64) maxr = 64;
    int tid = threadIdx.x;
    int l = tid & 63, wv = tid >> 6;
    int l31 = l & 31, half = l >> 5;
    int nt = wv & 1, mt0 = (wv >> 1) * 2;
    floatx16 acc[2];
#pragma unroll
    for (int t = 0; t < 2; ++t)
#pragma unroll
        for (int q = 0; q < 16; ++q) acc[t][q] = 0.0f;
    int xnode = row0 + nt * 32 + l31;
#pragma unroll
    for (int kt = 0; kt < 8; ++kt) {
        // plane kt, node xnode, half: one contiguous 2KB region per wave
        short8 xf = *(const short8*)&Ap4[((size_t)kt * n + xnode) * 2 + half];
#pragma unroll
        for (int t = 0; t < 2; ++t) {
            int c = (mt0 + t) * 32 + l31;
            short8 wf = *(const short8*)&Wt[c * 16 + (kt * 2 + half)];
            acc[t] = __builtin_amdgcn_mfma_f32_32x32x16_bf16(wf, xf, acc[t], 0, 0, 0);
        }
    }
    int node = nt * 32 + l31;
    float dv = (node < maxr) ? dinv[row0 + node] : 0.0f;

    if (outZ) {  // layer 1: direct planar write from registers (no LDS)
#pragma unroll
        for (int t = 0; t < 2; ++t) {
            int cb = (mt0 + t) * 32;
#pragma unroll
            for (int q = 0; q < 4; ++q) {
                float v[4];
#pragma unroll
                for (int m = 0; m < 4; ++m) {
                    int ch = cb + 8 * q + 4 * half + m;
                    float x_ = acc[t][q * 4 + m] + bias[ch];
                    x_ = fmaxf(x_, 0.0f);
                    v[m] = x_ * dv;
                }
                uint2 pk = make_uint2(f2bf(v[0]) | (f2bf(v[1]) << 16),
                                      f2bf(v[2]) | (f2bf(v[3]) << 16));
                int j = (cb >> 2) + 2 * q + half;  // uint2 index in 256B row
                if (node < maxr)
                    outZ[((size_t)(j >> 2) * n + row0 + node) * 4 + (j & 3)] = pk;
            }
        }
    }

    if (outP) {  // layer 2: stage z2 rows in LDS, P = z2 @ W3, store Ps
        char* outb = (char*)ldsX;
#pragma unroll
        for (int t = 0; t < 2; ++t) {
            int cb = (mt0 + t) * 32;
#pragma unroll
            for (int q = 0; q < 4; ++q) {
                float v[4];
#pragma unroll
                for (int m = 0; m < 4; ++m) {
                    int ch = cb + 8 * q + 4 * half + m;
                    float x_ = acc[t][q * 4 + m] + bias[ch];
                    x_ = fmaxf(x_, 0.0f);
                    v[m] = x_ * dv;  // dv==0 for invalid rows -> zero rows
                }
                uint2 pk = make_uint2(f2bf(v[0]) | (f2bf(v[1]) << 16),
                                      f2bf(v[2]) | (f2bf(v[3]) << 16));
                int chunk = (cb >> 3) + q;
                *(uint2*)(outb + node * 256 + ((chunk ^ (node & 7)) * 16) + half * 8) = pk;
            }
        }
        __syncthreads();
        floatx16 accp;
#pragma unroll
        for (int q = 0; q < 16; ++q) accp[q] = 0.0f;
        int xrow = nt * 32 + l31, xsw = xrow & 7;
        int mt = wv >> 1;
#pragma unroll
        for (int kt = 0; kt < 8; ++kt) {
            int chunk = kt * 2 + half;
            short8 xf = *(const short8*)&ldsX[xrow * 16 + (chunk ^ xsw)];
            int c = mt * 32 + l31;
            short8 wf = *(const short8*)&WtP[c * 16 + chunk];
            accp = __builtin_amdgcn_mfma_f32_32x32x16_bf16(wf, xf, accp, 0, 0, 0);
        }
        __syncthreads();  // all reads of z2 tile done before overwrite
        int cb = mt * 32;
#pragma unroll
        for (int q = 0; q < 4; ++q) {
            uint2 pk = make_uint2(f2bf(accp[q * 4 + 0]) | (f2bf(accp[q * 4 + 1]) << 16),
                                  f2bf(accp[q * 4 + 2]) | (f2bf(accp[q * 4 + 3]) << 16));
            int chunk = (cb >> 3) + q;
            *(uint2*)(outb + node * 128 + ((chunk ^ (node & 7)) * 16) + half * 8) = pk;
        }
        __syncthreads();
        for (int idx = tid; idx < maxr * 8; idx += THREADS) {
            int r = idx >> 3, c = idx & 7;
            outP[(size_t)(row0 + r) * 8 + c] = *(uint4*)(outb + r * 128 + ((c ^ (r & 7)) * 16));
        }
    }
}

// ---- layer-3 agg fused with mean-pool accumulation (unchanged) --------------
__global__ __launch_bounds__(THREADS) void agg_pool(const uint4* __restrict__ Ps,
                                                    const int* __restrict__ row_start,
                                                    const int* __restrict__ row_end,
                                                    const int* __restrict__ esrc,
                                                    const float* __restrict__ dinv,
                                                    const float* __restrict__ bias,
                                                    const int* __restrict__ batch,
                                                    const uint4* __restrict__ zrow,
                                                    float* __restrict__ gsum, int n) {
    __shared__ float gpart[32][65];
    __shared__ int used[32];
    int tid = threadIdx.x;
    int lane = tid & 7, grp = tid >> 3;
    int node = blockIdx.x * 32 + grp;
    bool valid = node < n;
    int nd = valid ? node : (n - 1);
    if (tid < 32) used[tid] = 0;
    for (int idx = tid; idx < 2048; idx += THREADS) gpart[idx >> 6][idx & 63] = 0.0f;
    __syncthreads();
    int gmin = batch[blockIdx.x * 32];
    const uint4* zl = zrow + lane;

    float ac[8] = {0, 0, 0, 0, 0, 0, 0, 0};
    bf8_acc(Ps[(size_t)nd * 8 + lane], ac);
    float dv = valid ? dinv[nd] : 0.0f;
    int s = row_start[nd], e = row_end[nd];
    int i = s;
    int nmain = (e - s) >> 3;
    if (nmain > 0) {
        int s0 = esrc[i], s1 = esrc[i + 1], s2 = esrc[i + 2], s3 = esrc[i + 3];
        int s4 = esrc[i + 4], s5 = esrc[i + 5], s6 = esrc[i + 6], s7 = esrc[i + 7];
        for (int m = 0; m < nmain; ++m) {
            uint4 v0 = Ps[(size_t)s0 * 8 + lane];
            uint4 v1 = Ps[(size_t)s1 * 8 + lane];
            uint4 v2 = Ps[(size_t)s2 * 8 + lane];
            uint4 v3 = Ps[(size_t)s3 * 8 + lane];
            uint4 v4 = Ps[(size_t)s4 * 8 + lane];
            uint4 v5 = Ps[(size_t)s5 * 8 + lane];
            uint4 v6 = Ps[(size_t)s6 * 8 + lane];
            uint4 v7 = Ps[(size_t)s7 * 8 + lane];
            int ni = i + 8;
            int t0 = esrc[ni], t1 = esrc[ni + 1], t2 = esrc[ni + 2], t3 = esrc[ni + 3];
            int t4 = esrc[ni + 4], t5 = esrc[ni + 5], t6 = esrc[ni + 6], t7 = esrc[ni + 7];
            bf8_acc(v0, ac); bf8_acc(v1, ac); bf8_acc(v2, ac); bf8_acc(v3, ac);
            bf8_acc(v4, ac); bf8_acc(v5, ac); bf8_acc(v6, ac); bf8_acc(v7, ac);
            s0 = t0; s1 = t1; s2 = t2; s3 = t3;
            s4 = t4; s5 = t5; s6 = t6; s7 = t7;
            i = ni;
        }
    }
    if (i < e) {
        const uint4* p0 = (i + 0 < e) ? (Ps + ((size_t)esrc[i + 0] * 8 + lane)) : zl;
        const uint4* p1 = (i + 1 < e) ? (Ps + ((size_t)esrc[i + 1] * 8 + lane)) : zl;
        const uint4* p2 = (i + 2 < e) ? (Ps + ((size_t)esrc[i + 2] * 8 + lane)) : zl;
        const uint4* p3 = (i + 3 < e) ? (Ps + ((size_t)esrc[i + 3] * 8 + lane)) : zl;
        const uint4* p4 = (i + 4 < e) ? (Ps + ((size_t)esrc[i + 4] * 8 + lane)) : zl;
        const uint4* p5 = (i + 5 < e) ? (Ps + ((size_t)esrc[i + 5] * 8 + lane)) : zl;
        const uint4* p6 = (i + 6 < e) ? (Ps + ((size_t)esrc[i + 6] * 8 + lane)) : zl;
        const uint4* p7 = (i + 7 < e) ? (Ps + ((size_t)esrc[i + 7] * 8 + lane)) : zl;
        uint4 v0 = *p0; uint4 v1 = *p1; uint4 v2 = *p2; uint4 v3 = *p3;
        uint4 v4 = *p4; uint4 v5 = *p5; uint4 v6 = *p6; uint4 v7 = *p7;
        bf8_acc(v0, ac); bf8_acc(v1, ac); bf8_acc(v2, ac); bf8_acc(v3, ac);
        bf8_acc(v4, ac); bf8_acc(v5, ac); bf8_acc(v6, ac); bf8_acc(v7, ac);
    }
    float4 b0 = ((const float4*)bias)[lane * 2];
    float4 b1 = ((const float4*)bias)[lane * 2 + 1];
    float h[8];
    h[0] = valid ? fmaf(dv, ac[0], b0.x) : 0.0f;
    h[1] = valid ? fmaf(dv, ac[1], b0.y) : 0.0f;
    h[2] = valid ? fmaf(dv, ac[2], b0.z) : 0.0f;
    h[3] = valid ? fmaf(dv, ac[3], b0.w) : 0.0f;
    h[4] = valid ? fmaf(dv, ac[4], b1.x) : 0.0f;
    h[5] = valid ? fmaf(dv, ac[5], b1.y) : 0.0f;
    h[6] = valid ? fmaf(dv, ac[6], b1.z) : 0.0f;
    h[7] = valid ? fmaf(dv, ac[7], b1.w) : 0.0f;
    int g = batch[nd];
    int slot = g - gmin;

    int s0w = __shfl(slot, 0, 64);
    bool fast = __all(slot == s0w) && (s0w >= 0) && (s0w < 32);
    if (fast) {
#pragma unroll
        for (int j = 0; j < 8; ++j) {
            float v = h[j];
            v += __shfl_xor(v, 8, 64);
            v += __shfl_xor(v, 16, 64);
            v += __shfl_xor(v, 32, 64);
            h[j] = v;
        }
        if ((tid & 63) < 8) {
            used[s0w] = 1;
#pragma unroll
            for (int j = 0; j < 8; ++j) atomicAdd(&gpart[s0w][lane * 8 + j], h[j]);
        }
    } else if (valid) {
        if (slot >= 0 && slot < 32) {
            if (lane == 0) used[slot] = 1;
#pragma unroll
            for (int j = 0; j < 8; ++j) atomicAdd(&gpart[slot][lane * 8 + j], h[j]);
        } else {
#pragma unroll
            for (int j = 0; j < 8; ++j) atomicAdd(&gsum[(size_t)g * 64 + lane * 8 + j], h[j]);
        }
    }
    __syncthreads();
    for (int idx = tid; idx < 2048; idx += THREADS) {
        int sl = idx >> 6, ch = idx & 63;
        if (used[sl]) atomicAdd(&gsum[(size_t)(gmin + sl) * 64 + ch], gpart[sl][ch]);
    }
}

// ---- finalize: mean + FC ---------------------------------------------------
__device__ __forceinline__ int dev_lower_bound(const int* a, int n, int key) {
    int lo = 0, hi = n;
    while (lo < hi) {
        int mid = (lo + hi) >> 1;
        if (a[mid] < key) lo = mid + 1;
        else hi = mid;
    }
    return lo;
}

__global__ __launch_bounds__(128) void finalize_fc(const float* __restrict__ gsum,
                                                   const int* __restrict__ batch, int n,
                                                   const float* __restrict__ Wfc,
                                                   const float* __restrict__ bfc,
                                                   float* __restrict__ out) {
    __shared__ float gm[64 * 64];
    __shared__ float cnt[64];
    int t = threadIdx.x;
    if (t < 64)
        cnt[t] = (float)(dev_lower_bound(batch, n, t + 1) - dev_lower_bound(batch, n, t));
    __syncthreads();
    for (int i = t; i < 64 * 64; i += 128) gm[i] = gsum[i] / fmaxf(cnt[i >> 6], 1.0f);
    __syncthreads();
    int g = t >> 1, cls = t & 1;
    float acc = bfc[cls];
    for (int c = 0; c < 64; ++c) acc = fmaf(gm[g * 64 + c], Wfc[c * 2 + cls], acc);
    out[g * 2 + cls] = acc;
}

extern "C" void kernel_launch(void* const* d_in, const int* in_sizes, int n_in,
                              void* d_out, int out_size, void* d_ws, size_t ws_size,
                              hipStream_t stream) {
    const float* x    = (const float*)d_in[0];
    const int*   ei   = (const int*)d_in[1];
    const int*   batch= (const int*)d_in[2];
    const float* W1   = (const float*)d_in[3];
    const float* b1   = (const float*)d_in[4];
    const float* W2   = (const float*)d_in[5];
    const float* b2   = (const float*)d_in[6];
    const float* W3   = (const float*)d_in[7];
    const float* b3   = (const float*)d_in[8];
    const float* Wfc  = (const float*)d_in[9];
    const float* bfc  = (const float*)d_in[10];
    float* out = (float*)d_out;

    const int N = in_sizes[2];        // 100000
    const int E = in_sizes[1] / 2;    // 1600000
    const int* esrc_in = ei;          // edge_index[0]
    const int* edst_in = ei + E;      // edge_index[1]
    const int nbuck = (N + BSIZE - 1) >> BSHIFT;  // 196
    const int nscat = (E + 4095) / 4096;          // 391
    const int ntick = (N + 255) / 256;            // 391 tickets per slice

    // workspace layout (~101 MB); pairs aliases bufC (disjoint lifetimes)
    uint4* bufA      = (uint4*)d_ws;                  // N*16 (z1 planar)
    uint4* bufB      = bufA + (size_t)N * 16;         // N*16 (z2 planar)
    uint4* bufC      = bufB + (size_t)N * 16;         // N*8  (Ps row-major)
    int*   pairs     = (int*)bufC;                    // nbuck*SREG (<= bufC)
    int*   esrc      = (int*)(bufC + (size_t)N * 8);  // nbuck*SREG + 8
    int*   row_start = esrc + (size_t)nbuck * SREG + 8;  // N
    int*   row_end   = row_start + N;                 // N
    int*   pmeta     = row_end + N;                   // N  (rs<<9 | deg)
    float* dinv      = (float*)(pmeta + N);           // N
    int*   bcursor   = (int*)(dinv + N);              // 512  ┐
    float* gsum      = (float*)(bcursor + 512);       // 4096 ├ one memset region
    float* zrow      = gsum + 64 * 64;                // 64   │
    int*   wctr      = (int*)(zrow + 64);             // 16   ┘
    uint4* Wt1       = (uint4*)(wctr + 16);           // 2048
    uint4* Wt2       = Wt1 + 2048;                    // 2048
    uint4* Wt3       = Wt2 + 2048;                    // 1024
    uint4* Abuf      = Wt3 + 1024;                    // N*16 + 2048 pad (A planar)

    // ---- build + prep ----
    hipMemsetAsync(bcursor, 0, (512 + 64 * 64 + 64 + 16) * sizeof(int), stream);
    bucket_scatter<<<nscat + 20, THREADS, 0, stream>>>(esrc_in, edst_in, bcursor, pairs, E,
                                                       nscat, W1, W2, W3, Wt1, Wt2, Wt3);
    bucket_fill<<<nbuck, 1024, 0, stream>>>(pairs, bcursor, row_start, row_end, pmeta, dinv,
                                            esrc, x, bufA, N);

    const int GB = (N + 63) / 64;

    // ---- layer 1: gather (XCD planes) -> gemm (writes z2 planar) ----
    gather_slice<<<NSL * ntick, THREADS, 0, stream>>>((const uint2*)bufA, pmeta, esrc,
                                                      (const uint2*)zrow, (uint2*)Abuf,
                                                      wctr, N, ntick);
    gemm_layer<<<GB, THREADS, 0, stream>>>(Abuf, Wt1, dinv, b1, (uint2*)bufB,
                                           nullptr, nullptr, N);
    // ---- layer 2: gather -> gemm (P = z2@W3 only; z2 global store dropped) --
    gather_slice<<<NSL * ntick, THREADS, 0, stream>>>((const uint2*)bufB, pmeta, esrc,
                                                      (const uint2*)zrow, (uint2*)Abuf,
                                                      wctr + 8, N, ntick);
    gemm_layer<<<GB, THREADS, 0, stream>>>(Abuf, Wt2, dinv, b2, nullptr,
                                           Wt3, bufC, N);

    // ---- layer 3 agg + pool, finalize ----
    agg_pool<<<(N + 31) / 32, THREADS, 0, stream>>>(bufC, row_start, row_end, esrc, dinv, b3,
                                                    batch, (const uint4*)zrow, gsum, N);
    finalize_fc<<<1, 128, 0, stream>>>(gsum, batch, N, Wfc, bfc, out);
}

// Round 13
// 353.721 us; speedup vs baseline: 2.8021x; 2.8021x over previous
//
#include <hip/hip_runtime.h>
#include <hip/hip_bf16.h>

// ---------------------------------------------------------------------------
// GCN via agg-commute: agg(XW) == agg(X)W. z = dinv (.) h stored bf16.
// Fused layer: A_i = dinv_i(sum z[src] + z[i]) -> LDS -> MFMA A@W -> +b, relu,
// x dinv -> bf16. Layer3 P = z2@W3 fused into layer-2 epilogue; agg64 fused
// with mean-pool (wave-uniform shfl fast path).
// R22: revert to R18/R20 (best: 351.6us, reproduced 354.3). R21's XCD-plane
//   gather CONFIRMED the governing model: FETCH fell 187->78MB (hit-rate up,
//   as predicted) yet dur tripled -- the gather is REQUEST-RATE bound
//   (~40-45G L2 line-requests/s device-wide), not miss-byte bound. R20's
//   16-lane x 256B row gather is already at the minimum requests/edge
//   (1 instr, 4 lines, all bytes useful). Four gather attacks (R11 MLP,
//   R12 channel-split, R19 src-sort, R21 plane-partition) all bounced off
//   this ceiling -> ~82us/layer is the structural floor.
// ---------------------------------------------------------------------------

#define THREADS 256
#define BSHIFT 9
#define BSIZE 512
#define SREG 12288  // static slots per bucket region

typedef __attribute__((ext_vector_type(8))) short short8;
typedef __attribute__((ext_vector_type(16))) float floatx16;

__device__ __forceinline__ unsigned f2bf(float f) {  // fp32 -> bf16 bits, RNE
    unsigned u = __float_as_uint(f);
    return (u + 0x7fffu + ((u >> 16) & 1u)) >> 16;
}

__device__ __forceinline__ void bf8_acc(uint4 v, float* ac) {
    ac[0] += __uint_as_float(v.x << 16);
    ac[1] += __uint_as_float(v.x & 0xffff0000u);
    ac[2] += __uint_as_float(v.y << 16);
    ac[3] += __uint_as_float(v.y & 0xffff0000u);
    ac[4] += __uint_as_float(v.z << 16);
    ac[5] += __uint_as_float(v.z & 0xffff0000u);
    ac[6] += __uint_as_float(v.w << 16);
    ac[7] += __uint_as_float(v.w & 0xffff0000u);
}

// ---- prep: W^T bf16 pack helper --------------------------------------------
__device__ __forceinline__ void wt_pack(const float* W, uint4* Wtp, int C, int li) {
    int c = li >> 4, ch = li & 15;
    unsigned r[8];
#pragma unroll
    for (int j = 0; j < 8; ++j) r[j] = f2bf(W[(size_t)(ch * 8 + j) * C + c]);
    uint4 o;
    o.x = r[0] | (r[1] << 16);
    o.y = r[2] | (r[3] << 16);
    o.z = r[4] | (r[5] << 16);
    o.w = r[6] | (r[7] << 16);
    Wtp[li] = o;
}

// ---- bucketed scatter to static regions ------------------------------------
// blocks [0,nscat): scatter; blocks [nscat,nscat+20): W^T packing.
// chunk = 4096 edges/block (16/thread); pair = (src<<9) | (dst & 511).
// bcursor starts at 0; after this kernel bcursor[b] == bucket b's edge count.
__global__ __launch_bounds__(THREADS) void bucket_scatter(const int* __restrict__ src,
                                                          const int* __restrict__ dst,
                                                          int* __restrict__ bcursor,
                                                          int* __restrict__ pairs,
                                                          int E, int nscat,
                                                          const float* __restrict__ W1,
                                                          const float* __restrict__ W2,
                                                          const float* __restrict__ W3,
                                                          uint4* __restrict__ Wt1,
                                                          uint4* __restrict__ Wt2,
                                                          uint4* __restrict__ Wt3) {
    if (blockIdx.x >= nscat) {
        int k = (blockIdx.x - nscat) * THREADS + threadIdx.x;
        if (k < 2048) wt_pack(W1, Wt1, 128, k);
        else if (k < 4096) wt_pack(W2, Wt2, 128, k - 2048);
        else if (k < 5120) wt_pack(W3, Wt3, 64, k - 4096);
        return;
    }
    __shared__ int cnt[BSIZE];
    __shared__ int base[BSIZE];
    for (int i = threadIdx.x; i < BSIZE; i += THREADS) cnt[i] = 0;
    __syncthreads();
    int e0 = blockIdx.x * 4096;
    int myb[16], myrank[16], mypk[16];
#pragma unroll
    for (int j = 0; j < 16; ++j) {
        int e = e0 + j * THREADS + threadIdx.x;
        myb[j] = -1;
        if (e < E) {
            int d = dst[e];
            mypk[j] = (src[e] << BSHIFT) | (d & (BSIZE - 1));
            myb[j] = d >> BSHIFT;
            myrank[j] = atomicAdd(&cnt[myb[j]], 1);
        }
    }
    __syncthreads();
    for (int i = threadIdx.x; i < BSIZE; i += THREADS) {
        int c = cnt[i];
        base[i] = c ? atomicAdd(&bcursor[i], c) : 0;
    }
    __syncthreads();
#pragma unroll
    for (int j = 0; j < 16; ++j)
        if (myb[j] >= 0) {
            int pos = base[myb[j]] + myrank[j];
            if (pos < SREG)  // impossible by binomial tail; guard vs corruption
                pairs[(size_t)myb[j] * SREG + pos] = mypk[j];
        }
}

// one block per bucket, 1024 threads: local histogram/scan -> row_start,
// row_end, dinv, esrc (static region); then fused prep_x for the bucket's
// 512 nodes (z1 = bf16(dinv (.) x); x slab contiguous 256KB).
__global__ __launch_bounds__(1024) void bucket_fill(const int* __restrict__ pairs,
                                                    const int* __restrict__ bcount,
                                                    int* __restrict__ row_start,
                                                    int* __restrict__ row_end,
                                                    float* __restrict__ dinv,
                                                    int* __restrict__ esrc,
                                                    const float* __restrict__ x,
                                                    uint4* __restrict__ Z, int N) {
    __shared__ int cnt[BSIZE];
    __shared__ int scn[BSIZE];
    __shared__ float sdv[BSIZE];
    int b = blockIdx.x, t = threadIdx.x;
    size_t rbase = (size_t)b * SREG;
    int total = bcount[b];
    if (total > SREG) total = SREG;
    if (t < BSIZE) cnt[t] = 0;
    __syncthreads();
    for (int i = t; i < total; i += 1024) atomicAdd(&cnt[pairs[rbase + i] & (BSIZE - 1)], 1);
    __syncthreads();
    int v = 0;
    if (t < BSIZE) {
        v = cnt[t];
        scn[t] = v;
    }
    __syncthreads();
    for (int off = 1; off < 512; off <<= 1) {
        int tv = (t >= off && t < BSIZE) ? scn[t - off] : 0;
        __syncthreads();
        if (t < BSIZE) scn[t] += tv;
        __syncthreads();
    }
    if (t < BSIZE) {
        int excl = scn[t] - v;
        int g = (b << BSHIFT) + t;
        float dv = rsqrtf(1.0f + (float)v);  // deg = 1 + in-degree (self-loop)
        if (g < N) {
            row_start[g] = (int)rbase + excl;
            row_end[g] = (int)rbase + excl + v;
            dinv[g] = dv;
        }
        sdv[t] = dv;
        scn[t] = excl;  // reuse as cursor
    }
    __syncthreads();
    for (int i = t; i < total; i += 1024) {
        int p = pairs[rbase + i];
        int r = atomicAdd(&scn[p & (BSIZE - 1)], 1);
        esrc[rbase + r] = ((unsigned)p) >> BSHIFT;
    }
    // ---- fused prep_x: this bucket's nodes, dinv from LDS ----
    int g0 = b << BSHIFT;
    for (int idx = t; idx < BSIZE * 16; idx += 1024) {
        int rl = idx >> 4;
        int g = g0 + rl;
        if (g >= N) break;  // rl monotonic per thread
        int c = idx & 15;
        float dv = sdv[rl];
        const float* p = x + (size_t)g * 128 + c * 8;
        float4 a = *(const float4*)p;
        float4 bb = *(const float4*)(p + 4);
        uint4 o;
        o.x = f2bf(a.x * dv) | (f2bf(a.y * dv) << 16);
        o.y = f2bf(a.z * dv) | (f2bf(a.w * dv) << 16);
        o.z = f2bf(bb.x * dv) | (f2bf(bb.y * dv) << 16);
        o.w = f2bf(bb.z * dv) | (f2bf(bb.w * dv) << 16);
        Z[(size_t)g * 16 + c] = o;
    }
}

// ---- fused layer: gather -> LDS -> MFMA -> epilogue (+optional P=z2@W3) ----
__global__ __launch_bounds__(THREADS) void fused_layer(const uint4* __restrict__ Z,
                                                       const uint4* __restrict__ Wt,
                                                       const int* __restrict__ row_start,
                                                       const int* __restrict__ row_end,
                                                       const int* __restrict__ esrc,
                                                       const float* __restrict__ dinv,
                                                       const float* __restrict__ bias,
                                                       const uint4* __restrict__ zrow,
                                                       uint4* __restrict__ out,
                                                       const uint4* __restrict__ WtP,
                                                       uint4* __restrict__ outP, int n) {
    __shared__ __align__(16) uint4 ldsX[64 * 16];  // 16KB: A-tile, reused for out-stage
    int row0 = blockIdx.x * 64;
    int maxr = n - row0;
    if (maxr > 64) maxr = 64;
    int tid = threadIdx.x;
    int lane = tid & 15, grp = tid >> 4;
    const uint4* zl = zrow + lane;

    // ---- gather phase: 16 lanes/node, 16 nodes concurrent, 4 rounds ----
    for (int round = 0; round < 4; ++round) {
        int r = round * 16 + grp;
        int node = row0 + r;
        int nd = (node < n) ? node : (n - 1);
        float ac[8] = {0, 0, 0, 0, 0, 0, 0, 0};
        bf8_acc(Z[(size_t)nd * 16 + lane], ac);  // self term z[i]
        float dv = dinv[nd];                     // hoisted: in flight during gather
        int s = row_start[nd], e = row_end[nd];
        int i = s;
        int nmain = (e - s) >> 3;
        if (nmain > 0) {
            int s0 = esrc[i], s1 = esrc[i + 1], s2 = esrc[i + 2], s3 = esrc[i + 3];
            int s4 = esrc[i + 4], s5 = esrc[i + 5], s6 = esrc[i + 6], s7 = esrc[i + 7];
            for (int m = 0; m < nmain; ++m) {
                uint4 v0 = Z[(size_t)s0 * 16 + lane];
                uint4 v1 = Z[(size_t)s1 * 16 + lane];
                uint4 v2 = Z[(size_t)s2 * 16 + lane];
                uint4 v3 = Z[(size_t)s3 * 16 + lane];
                uint4 v4 = Z[(size_t)s4 * 16 + lane];
                uint4 v5 = Z[(size_t)s5 * 16 + lane];
                uint4 v6 = Z[(size_t)s6 * 16 + lane];
                uint4 v7 = Z[(size_t)s7 * 16 + lane];
                int ni = i + 8;
                // prefetch next chunk's esrc (overread <=7 ints: padded region)
                int t0 = esrc[ni], t1 = esrc[ni + 1], t2 = esrc[ni + 2], t3 = esrc[ni + 3];
                int t4 = esrc[ni + 4], t5 = esrc[ni + 5], t6 = esrc[ni + 6], t7 = esrc[ni + 7];
                bf8_acc(v0, ac); bf8_acc(v1, ac); bf8_acc(v2, ac); bf8_acc(v3, ac);
                bf8_acc(v4, ac); bf8_acc(v5, ac); bf8_acc(v6, ac); bf8_acc(v7, ac);
                s0 = t0; s1 = t1; s2 = t2; s3 = t3;
                s4 = t4; s5 = t5; s6 = t6; s7 = t7;
                i = ni;
            }
        }
        if (i < e) {  // masked branchless 8-wide tail (1..7 valid slots)
            const uint4* p0 = (i + 0 < e) ? (Z + ((size_t)esrc[i + 0] * 16 + lane)) : zl;
            const uint4* p1 = (i + 1 < e) ? (Z + ((size_t)esrc[i + 1] * 16 + lane)) : zl;
            const uint4* p2 = (i + 2 < e) ? (Z + ((size_t)esrc[i + 2] * 16 + lane)) : zl;
            const uint4* p3 = (i + 3 < e) ? (Z + ((size_t)esrc[i + 3] * 16 + lane)) : zl;
            const uint4* p4 = (i + 4 < e) ? (Z + ((size_t)esrc[i + 4] * 16 + lane)) : zl;
            const uint4* p5 = (i + 5 < e) ? (Z + ((size_t)esrc[i + 5] * 16 + lane)) : zl;
            const uint4* p6 = (i + 6 < e) ? (Z + ((size_t)esrc[i + 6] * 16 + lane)) : zl;
            const uint4* p7 = (i + 7 < e) ? (Z + ((size_t)esrc[i + 7] * 16 + lane)) : zl;
            uint4 v0 = *p0; uint4 v1 = *p1; uint4 v2 = *p2; uint4 v3 = *p3;
            uint4 v4 = *p4; uint4 v5 = *p5; uint4 v6 = *p6; uint4 v7 = *p7;
            bf8_acc(v0, ac); bf8_acc(v1, ac); bf8_acc(v2, ac); bf8_acc(v3, ac);
            bf8_acc(v4, ac); bf8_acc(v5, ac); bf8_acc(v6, ac); bf8_acc(v7, ac);
        }
        // A_i = dinv_i * (sum z[src] + z[i])
        uint4 o;
        o.x = f2bf(ac[0] * dv) | (f2bf(ac[1] * dv) << 16);
        o.y = f2bf(ac[2] * dv) | (f2bf(ac[3] * dv) << 16);
        o.z = f2bf(ac[4] * dv) | (f2bf(ac[5] * dv) << 16);
        o.w = f2bf(ac[6] * dv) | (f2bf(ac[7] * dv) << 16);
        ldsX[r * 16 + (lane ^ (r & 7))] = o;
    }
    __syncthreads();

    // ---- MFMA phase: D = W^T A^T ; W read from L2-hot global ----
    int l = tid & 63, wv = tid >> 6;
    int l31 = l & 31, half = l >> 5;
    int nt = wv & 1, mt0 = (wv >> 1) * 2;
    floatx16 acc[2];
#pragma unroll
    for (int t = 0; t < 2; ++t)
#pragma unroll
        for (int q = 0; q < 16; ++q) acc[t][q] = 0.0f;
    int xrow = nt * 32 + l31, xsw = xrow & 7;
#pragma unroll
    for (int kt = 0; kt < 8; ++kt) {
        int chunk = kt * 2 + half;
        short8 xf = *(const short8*)&ldsX[xrow * 16 + (chunk ^ xsw)];
#pragma unroll
        for (int t = 0; t < 2; ++t) {
            int c = (mt0 + t) * 32 + l31;
            short8 wf = *(const short8*)&Wt[c * 16 + chunk];
            acc[t] = __builtin_amdgcn_mfma_f32_32x32x16_bf16(wf, xf, acc[t], 0, 0, 0);
        }
    }
    __syncthreads();

    // ---- epilogue: +bias, relu, x dinv(node), pack bf16 -> LDS -> store ----
    int node = nt * 32 + l31;
    float dv = (node < maxr) ? dinv[row0 + node] : 0.0f;
    char* outb = (char*)ldsX;
#pragma unroll
    for (int t = 0; t < 2; ++t) {
        int cb = (mt0 + t) * 32;
#pragma unroll
        for (int q = 0; q < 4; ++q) {
            float v[4];
#pragma unroll
            for (int m = 0; m < 4; ++m) {
                int ch = cb + 8 * q + 4 * half + m;
                float x_ = acc[t][q * 4 + m] + bias[ch];
                x_ = fmaxf(x_, 0.0f);  // relu (both fused layers use it)
                v[m] = x_ * dv;        // pre-scale for next layer's gather
            }
            uint2 pk = make_uint2(f2bf(v[0]) | (f2bf(v[1]) << 16),
                                  f2bf(v[2]) | (f2bf(v[3]) << 16));
            int chunk = (cb >> 3) + q;
            *(uint2*)(outb + node * 256 + ((chunk ^ (node & 7)) * 16) + half * 8) = pk;
        }
    }
    __syncthreads();
    for (int idx = tid; idx < maxr * 16; idx += THREADS) {
        int r = idx >> 4, c = idx & 15;
        out[(size_t)(row0 + r) * 16 + c] = *(uint4*)(outb + r * 256 + ((c ^ (r & 7)) * 16));
    }

    // ---- optional fused P = z2 @ W3 (layer-2 only): z2 tile is in outb -----
    if (outP) {
        floatx16 accp;
#pragma unroll
        for (int q = 0; q < 16; ++q) accp[q] = 0.0f;
        int mt = wv >> 1;  // 0..1 -> 64 out channels
#pragma unroll
        for (int kt = 0; kt < 8; ++kt) {
            int chunk = kt * 2 + half;
            short8 xf = *(const short8*)&ldsX[xrow * 16 + (chunk ^ xsw)];
            int c = mt * 32 + l31;
            short8 wf = *(const short8*)&WtP[c * 16 + chunk];
            accp = __builtin_amdgcn_mfma_f32_32x32x16_bf16(wf, xf, accp, 0, 0, 0);
        }
        __syncthreads();  // all reads of outb (z2) done before overwrite
        int cb = mt * 32;
#pragma unroll
        for (int q = 0; q < 4; ++q) {
            uint2 pk = make_uint2(f2bf(accp[q * 4 + 0]) | (f2bf(accp[q * 4 + 1]) << 16),
                                  f2bf(accp[q * 4 + 2]) | (f2bf(accp[q * 4 + 3]) << 16));
            int chunk = (cb >> 3) + q;
            *(uint2*)(outb + node * 128 + ((chunk ^ (node & 7)) * 16) + half * 8) = pk;
        }
        __syncthreads();
        for (int idx = tid; idx < maxr * 8; idx += THREADS) {
            int r = idx >> 3, c = idx & 7;
            outP[(size_t)(row0 + r) * 8 + c] = *(uint4*)(outb + r * 128 + ((c ^ (r & 7)) * 16));
        }
    }
}

// ---- layer-3 agg fused with mean-pool accumulation -------------------------
__global__ __launch_bounds__(THREADS) void agg_pool(const uint4* __restrict__ Ps,
                                                    const int* __restrict__ row_start,
                                                    const int* __restrict__ row_end,
                                                    const int* __restrict__ esrc,
                                                    const float* __restrict__ dinv,
                                                    const float* __restrict__ bias,
                                                    const int* __restrict__ batch,
                                                    const uint4* __restrict__ zrow,
                                                    float* __restrict__ gsum, int n) {
    __shared__ float gpart[32][65];  // pad 65: lanes hit distinct banks
    __shared__ int used[32];
    int tid = threadIdx.x;
    int lane = tid & 7, grp = tid >> 3;
    int node = blockIdx.x * 32 + grp;
    bool valid = node < n;
    int nd = valid ? node : (n - 1);
    if (tid < 32) used[tid] = 0;
    for (int idx = tid; idx < 2048; idx += THREADS) gpart[idx >> 6][idx & 63] = 0.0f;
    __syncthreads();
    int gmin = batch[blockIdx.x * 32];  // block's first node is always < n
    const uint4* zl = zrow + lane;

    float ac[8] = {0, 0, 0, 0, 0, 0, 0, 0};
    bf8_acc(Ps[(size_t)nd * 8 + lane], ac);  // self
    float dv = valid ? dinv[nd] : 0.0f;
    int s = row_start[nd], e = row_end[nd];
    int i = s;
    int nmain = (e - s) >> 3;
    if (nmain > 0) {
        int s0 = esrc[i], s1 = esrc[i + 1], s2 = esrc[i + 2], s3 = esrc[i + 3];
        int s4 = esrc[i + 4], s5 = esrc[i + 5], s6 = esrc[i + 6], s7 = esrc[i + 7];
        for (int m = 0; m < nmain; ++m) {
            uint4 v0 = Ps[(size_t)s0 * 8 + lane];
            uint4 v1 = Ps[(size_t)s1 * 8 + lane];
            uint4 v2 = Ps[(size_t)s2 * 8 + lane];
            uint4 v3 = Ps[(size_t)s3 * 8 + lane];
            uint4 v4 = Ps[(size_t)s4 * 8 + lane];
            uint4 v5 = Ps[(size_t)s5 * 8 + lane];
            uint4 v6 = Ps[(size_t)s6 * 8 + lane];
            uint4 v7 = Ps[(size_t)s7 * 8 + lane];
            int ni = i + 8;
            int t0 = esrc[ni], t1 = esrc[ni + 1], t2 = esrc[ni + 2], t3 = esrc[ni + 3];
            int t4 = esrc[ni + 4], t5 = esrc[ni + 5], t6 = esrc[ni + 6], t7 = esrc[ni + 7];
            bf8_acc(v0, ac); bf8_acc(v1, ac); bf8_acc(v2, ac); bf8_acc(v3, ac);
            bf8_acc(v4, ac); bf8_acc(v5, ac); bf8_acc(v6, ac); bf8_acc(v7, ac);
            s0 = t0; s1 = t1; s2 = t2; s3 = t3;
            s4 = t4; s5 = t5; s6 = t6; s7 = t7;
            i = ni;
        }
    }
    if (i < e) {  // masked branchless 8-wide tail
        const uint4* p0 = (i + 0 < e) ? (Ps + ((size_t)esrc[i + 0] * 8 + lane)) : zl;
        const uint4* p1 = (i + 1 < e) ? (Ps + ((size_t)esrc[i + 1] * 8 + lane)) : zl;
        const uint4* p2 = (i + 2 < e) ? (Ps + ((size_t)esrc[i + 2] * 8 + lane)) : zl;
        const uint4* p3 = (i + 3 < e) ? (Ps + ((size_t)esrc[i + 3] * 8 + lane)) : zl;
        const uint4* p4 = (i + 4 < e) ? (Ps + ((size_t)esrc[i + 4] * 8 + lane)) : zl;
        const uint4* p5 = (i + 5 < e) ? (Ps + ((size_t)esrc[i + 5] * 8 + lane)) : zl;
        const uint4* p6 = (i + 6 < e) ? (Ps + ((size_t)esrc[i + 6] * 8 + lane)) : zl;
        const uint4* p7 = (i + 7 < e) ? (Ps + ((size_t)esrc[i + 7] * 8 + lane)) : zl;
        uint4 v0 = *p0; uint4 v1 = *p1; uint4 v2 = *p2; uint4 v3 = *p3;
        uint4 v4 = *p4; uint4 v5 = *p5; uint4 v6 = *p6; uint4 v7 = *p7;
        bf8_acc(v0, ac); bf8_acc(v1, ac); bf8_acc(v2, ac); bf8_acc(v3, ac);
        bf8_acc(v4, ac); bf8_acc(v5, ac); bf8_acc(v6, ac); bf8_acc(v7, ac);
    }
    float4 b0 = ((const float4*)bias)[lane * 2];
    float4 b1 = ((const float4*)bias)[lane * 2 + 1];
    float h[8];
    h[0] = valid ? fmaf(dv, ac[0], b0.x) : 0.0f;
    h[1] = valid ? fmaf(dv, ac[1], b0.y) : 0.0f;
    h[2] = valid ? fmaf(dv, ac[2], b0.z) : 0.0f;
    h[3] = valid ? fmaf(dv, ac[3], b0.w) : 0.0f;
    h[4] = valid ? fmaf(dv, ac[4], b1.x) : 0.0f;
    h[5] = valid ? fmaf(dv, ac[5], b1.y) : 0.0f;
    h[6] = valid ? fmaf(dv, ac[6], b1.z) : 0.0f;
    h[7] = valid ? fmaf(dv, ac[7], b1.w) : 0.0f;
    int g = batch[nd];
    int slot = g - gmin;

    // wave-uniform fast path: 8 nodes of this wave share one slot (~98%)
    int s0w = __shfl(slot, 0, 64);
    bool fast = __all(slot == s0w) && (s0w >= 0) && (s0w < 32);
    if (fast) {
#pragma unroll
        for (int j = 0; j < 8; ++j) {
            float v = h[j];
            v += __shfl_xor(v, 8, 64);
            v += __shfl_xor(v, 16, 64);
            v += __shfl_xor(v, 32, 64);
            h[j] = v;
        }
        if ((tid & 63) < 8) {
            used[s0w] = 1;
#pragma unroll
            for (int j = 0; j < 8; ++j) atomicAdd(&gpart[s0w][lane * 8 + j], h[j]);
        }
    } else if (valid) {
        if (slot >= 0 && slot < 32) {
            if (lane == 0) used[slot] = 1;
#pragma unroll
            for (int j = 0; j < 8; ++j) atomicAdd(&gpart[slot][lane * 8 + j], h[j]);
        } else {  // only possible with empty graphs between nodes
#pragma unroll
            for (int j = 0; j < 8; ++j) atomicAdd(&gsum[(size_t)g * 64 + lane * 8 + j], h[j]);
        }
    }
    __syncthreads();
    for (int idx = tid; idx < 2048; idx += THREADS) {
        int sl = idx >> 6, ch = idx & 63;
        if (used[sl]) atomicAdd(&gsum[(size_t)(gmin + sl) * 64 + ch], gpart[sl][ch]);
    }
}

// ---- finalize: mean + FC ---------------------------------------------------
__device__ __forceinline__ int dev_lower_bound(const int* a, int n, int key) {
    int lo = 0, hi = n;
    while (lo < hi) {
        int mid = (lo + hi) >> 1;
        if (a[mid] < key) lo = mid + 1;
        else hi = mid;
    }
    return lo;
}

__global__ __launch_bounds__(128) void finalize_fc(const float* __restrict__ gsum,
                                                   const int* __restrict__ batch, int n,
                                                   const float* __restrict__ Wfc,
                                                   const float* __restrict__ bfc,
                                                   float* __restrict__ out) {
    __shared__ float gm[64 * 64];
    __shared__ float cnt[64];
    int t = threadIdx.x;
    if (t < 64)
        cnt[t] = (float)(dev_lower_bound(batch, n, t + 1) - dev_lower_bound(batch, n, t));
    __syncthreads();
    for (int i = t; i < 64 * 64; i += 128) gm[i] = gsum[i] / fmaxf(cnt[i >> 6], 1.0f);
    __syncthreads();
    int g = t >> 1, cls = t & 1;
    float acc = bfc[cls];
    for (int c = 0; c < 64; ++c) acc = fmaf(gm[g * 64 + c], Wfc[c * 2 + cls], acc);
    out[g * 2 + cls] = acc;
}

extern "C" void kernel_launch(void* const* d_in, const int* in_sizes, int n_in,
                              void* d_out, int out_size, void* d_ws, size_t ws_size,
                              hipStream_t stream) {
    const float* x    = (const float*)d_in[0];
    const int*   ei   = (const int*)d_in[1];
    const int*   batch= (const int*)d_in[2];
    const float* W1   = (const float*)d_in[3];
    const float* b1   = (const float*)d_in[4];
    const float* W2   = (const float*)d_in[5];
    const float* b2   = (const float*)d_in[6];
    const float* W3   = (const float*)d_in[7];
    const float* b3   = (const float*)d_in[8];
    const float* Wfc  = (const float*)d_in[9];
    const float* bfc  = (const float*)d_in[10];
    float* out = (float*)d_out;

    const int N = in_sizes[2];        // 100000
    const int E = in_sizes[1] / 2;    // 1600000
    const int* esrc_in = ei;          // edge_index[0]
    const int* edst_in = ei + E;      // edge_index[1]
    const int nbuck = (N + BSIZE - 1) >> BSHIFT;  // 196
    const int nscat = (E + 4095) / 4096;          // 391

    // workspace layout (~75 MB); pairs aliases bufC (disjoint lifetimes)
    uint4* bufA      = (uint4*)d_ws;                  // N*16 uint4 (z, bf16 packed)
    uint4* bufB      = bufA + (size_t)N * 16;         // N*16 uint4
    uint4* bufC      = bufB + (size_t)N * 16;         // N*8 uint4 (Ps)
    int*   pairs     = (int*)bufC;                    // nbuck*SREG ints (<= bufC)
    int*   esrc      = (int*)(bufC + (size_t)N * 8);  // nbuck*SREG + 8 ints
    int*   row_start = esrc + (size_t)nbuck * SREG + 8;  // N
    int*   row_end   = row_start + N;                 // N
    float* dinv      = (float*)(row_end + N);         // N
    int*   bcursor   = (int*)(dinv + N);              // 512  ┐
    float* gsum      = (float*)(bcursor + 512);       // 4096 ├ one memset region
    float* zrow      = gsum + 64 * 64;                // 64   ┘
    uint4* Wt1       = (uint4*)(zrow + 64);           // 2048
    uint4* Wt2       = Wt1 + 2048;                    // 2048
    uint4* Wt3       = Wt2 + 2048;                    // 1024

    // ---- build + prep (7 dispatches total) ----
    hipMemsetAsync(bcursor, 0, (512 + 64 * 64 + 64) * sizeof(int), stream);
    bucket_scatter<<<nscat + 20, THREADS, 0, stream>>>(esrc_in, edst_in, bcursor, pairs, E,
                                                       nscat, W1, W2, W3, Wt1, Wt2, Wt3);
    bucket_fill<<<nbuck, 1024, 0, stream>>>(pairs, bcursor, row_start, row_end, dinv, esrc,
                                            x, bufA, N);

    const int GB = (N + 63) / 64;

    // ---- layers (agg-commuted); P = z2@W3 fused into layer 2 ----
    fused_layer<<<GB, THREADS, 0, stream>>>(bufA, Wt1, row_start, row_end, esrc, dinv, b1,
                                            (const uint4*)zrow, bufB, nullptr, nullptr, N);
    fused_layer<<<GB, THREADS, 0, stream>>>(bufB, Wt2, row_start, row_end, esrc, dinv, b2,
                                            (const uint4*)zrow, bufA, Wt3, bufC, N);
    agg_pool<<<(N + 31) / 32, THREADS, 0, stream>>>(bufC, row_start, row_end, esrc, dinv, b3,
                                                    batch, (const uint4*)zrow, gsum, N);

    // ---- finalize ----
    finalize_fc<<<1, 128, 0, stream>>>(gsum, batch, N, Wfc, bfc, out);
}